// Round 11
// baseline (84.426 us; speedup 1.0000x reference)
//
#include <hip/hip_runtime.h>

#define F_   128
#define H_   16
#define E_   32
#define FG   8      // features per wave
#define NWAVES 16   // waves per block -> block covers all 128 features
#define NTHREADS (NWAVES * 64)   // 1024
#define BPB  32     // b rows per block (contiguous)

typedef float v2f __attribute__((ext_vector_type(2)));
typedef float v4f __attribute__((ext_vector_type(4)));

// The untested quadrant: PLAIN stores + LINEAR per-block streams.
// R7 geometry (block = 16 waves = all 128 features; per b one contiguous
// 16 KB row; 32 consecutive rows = 512 KB linear write stream per block),
// with plain (L2 write-back) stores instead of nontemporal. Theory: plain
// stores allocate dirty L2 lines; linear streams let L2 drain them as long
// sequential writebacks (the 7 TB/s fill kernel is exactly plain+linear),
// while strided chunks fragmented the writeback stream (R5's 65.8).
__global__ __launch_bounds__(NTHREADS, 4)
void nfe_kernel(const float* __restrict__ x,
                const float* __restrict__ W1,
                const float* __restrict__ b1,
                const float* __restrict__ W2,
                const float* __restrict__ b2,
                float* __restrict__ out)
{
    const int tid  = threadIdx.x;
    const int wave = tid >> 6;
    const int lane = tid & 63;

    const int b0 = blockIdx.x * BPB;

    const int f  = wave * FG + (lane >> 3);
    const int e4 = lane & 7;

    // ---- per-lane weight fragments in registers (as f32 pairs) ----
    v2f w1p[H_/2], b1p[H_/2];
    {
        const v2f* p1 = (const v2f*)(W1 + f * H_);
        const v2f* p2 = (const v2f*)(b1 + f * H_);
#pragma unroll
        for (int q = 0; q < H_/2; ++q) { w1p[q] = p1[q]; b1p[q] = p2[q]; }
    }
    v2f w2p[H_][2];   // [j][e-pair], covers this lane's 4 e's
#pragma unroll
    for (int j = 0; j < H_; ++j) {
        const v2f* q = (const v2f*)(W2 + (f * H_ + j) * E_ + e4 * 4);
        w2p[j][0] = q[0]; w2p[j][1] = q[1];
    }
    v2f b2p[2];
    {
        const v2f* q = (const v2f*)(b2 + f * E_ + e4 * 4);
        b2p[0] = q[0]; b2p[1] = q[1];
    }

    // ---- streaming loop over b: block writes 16 KB contiguous per b ----
    const float* xp = x + (size_t)b0 * F_ + f;
    // float4 index within b-row: f*8 + e4 = wave*64 + lane  (contiguous)
    v4f* op = (v4f*)out + (size_t)b0 * (F_ * E_ / 4) + tid;

    const v2f zero2 = {0.0f, 0.0f};

    float xv_next = *xp;
#pragma unroll 2
    for (int i = 0; i < BPB; ++i) {
        const float xv = xv_next;
        if (i + 1 < BPB) xv_next = xp[(i + 1) * F_];   // prefetch next b

        // layer 1: h pairs
        v2f x2 = {xv, xv};
        v2f h2[H_/2];
#pragma unroll
        for (int q = 0; q < H_/2; ++q) {
            v2f t = __builtin_elementwise_fma(x2, w1p[q], b1p[q]);
            h2[q] = __builtin_elementwise_max(t, zero2);
        }

        // layer 2: acc pairs, h broadcast via op_sel (lo then hi of h2[q])
        v2f a0 = b2p[0], a1 = b2p[1];
#pragma unroll
        for (int q = 0; q < H_/2; ++q) {
            asm("v_pk_fma_f32 %0, %1, %2, %0 op_sel:[0,0,0] op_sel_hi:[0,1,1]"
                : "+v"(a0) : "v"(h2[q]), "v"(w2p[2*q][0]));
            asm("v_pk_fma_f32 %0, %1, %2, %0 op_sel:[0,0,0] op_sel_hi:[0,1,1]"
                : "+v"(a1) : "v"(h2[q]), "v"(w2p[2*q][1]));
            asm("v_pk_fma_f32 %0, %1, %2, %0 op_sel:[1,0,0] op_sel_hi:[1,1,1]"
                : "+v"(a0) : "v"(h2[q]), "v"(w2p[2*q+1][0]));
            asm("v_pk_fma_f32 %0, %1, %2, %0 op_sel:[1,0,0] op_sel_hi:[1,1,1]"
                : "+v"(a1) : "v"(h2[q]), "v"(w2p[2*q+1][1]));
        }

        v4f acc = {a0.x, a0.y, a1.x, a1.y};
        op[i * (F_ * E_ / 4)] = acc;   // PLAIN store -> L2 write-back path
    }
}

extern "C" void kernel_launch(void* const* d_in, const int* in_sizes, int n_in,
                              void* d_out, int out_size, void* d_ws, size_t ws_size,
                              hipStream_t stream) {
    const float* x  = (const float*)d_in[0];
    const float* W1 = (const float*)d_in[1];
    const float* b1 = (const float*)d_in[2];
    const float* W2 = (const float*)d_in[3];
    const float* b2 = (const float*)d_in[4];
    float* out = (float*)d_out;

    const int B = in_sizes[0] / F_;   // 16384
    dim3 grid(B / BPB);               // 512 blocks, each a 512 KB linear stream
    nfe_kernel<<<grid, NTHREADS, 0, stream>>>(x, W1, b1, W2, b2, out);
}

// Round 12
// 84.312 us; speedup vs baseline: 1.0013x; 1.0013x over previous
//
#include <hip/hip_runtime.h>

#define F_   128
#define H_   16
#define E_   32
#define FG   8      // features per wave
#define NWAVES 16   // waves per block -> block covers all 128 features
#define NTHREADS (NWAVES * 64)   // 1024
#define NBLK 512    // grid size; B/NBLK = 32 iterations
#define NIT  32

typedef float v2f __attribute__((ext_vector_type(2)));
typedef float v4f __attribute__((ext_vector_type(4)));

// Fill-kernel emulation (the only observed ~7 TB/s writer): PLAIN stores +
// GRID-STRIDE row interleave. Iteration i of block j writes row i*512+j, so
// the 512 blocks collectively sweep one contiguous 8 MB window per iteration
// that slides across the 256 MB output — one global sequential write front,
// not 512 independent streams (R11, 84 us) nor strided chunks (R5, 66 us).
// Compute identical to champion (packed fp32, dist-1 x prefetch).
__global__ __launch_bounds__(NTHREADS, 4)
void nfe_kernel(const float* __restrict__ x,
                const float* __restrict__ W1,
                const float* __restrict__ b1,
                const float* __restrict__ W2,
                const float* __restrict__ b2,
                float* __restrict__ out)
{
    const int tid  = threadIdx.x;
    const int lane = tid & 63;

    const int f  = tid >> 3;     // 0..127  (wave w covers f in [8w, 8w+8))
    const int e4 = tid & 7;

    // ---- per-lane weight fragments in registers (as f32 pairs) ----
    v2f w1p[H_/2], b1p[H_/2];
    {
        const v2f* p1 = (const v2f*)(W1 + f * H_);
        const v2f* p2 = (const v2f*)(b1 + f * H_);
#pragma unroll
        for (int q = 0; q < H_/2; ++q) { w1p[q] = p1[q]; b1p[q] = p2[q]; }
    }
    v2f w2p[H_][2];   // [j][e-pair], covers this lane's 4 e's
#pragma unroll
    for (int j = 0; j < H_; ++j) {
        const v2f* q = (const v2f*)(W2 + (f * H_ + j) * E_ + e4 * 4);
        w2p[j][0] = q[0]; w2p[j][1] = q[1];
    }
    v2f b2p[2];
    {
        const v2f* q = (const v2f*)(b2 + f * E_ + e4 * 4);
        b2p[0] = q[0]; b2p[1] = q[1];
    }

    // ---- grid-stride row loop: row r = i*NBLK + blockIdx.x ----
    const int bid = blockIdx.x;
    v4f* const out4 = (v4f*)out;
    const size_t rowstride4 = F_ * E_ / 4;   // 1024 float4 per row

    const v2f zero2 = {0.0f, 0.0f};

    float xv_next = x[(size_t)bid * F_ + f];
#pragma unroll 2
    for (int i = 0; i < NIT; ++i) {
        const size_t r = (size_t)i * NBLK + bid;
        const float xv = xv_next;
        if (i + 1 < NIT)
            xv_next = x[((size_t)(i + 1) * NBLK + bid) * F_ + f];

        // layer 1: h pairs
        v2f x2 = {xv, xv};
        v2f h2[H_/2];
#pragma unroll
        for (int q = 0; q < H_/2; ++q) {
            v2f t = __builtin_elementwise_fma(x2, w1p[q], b1p[q]);
            h2[q] = __builtin_elementwise_max(t, zero2);
        }

        // layer 2: acc pairs, h broadcast via op_sel (lo then hi of h2[q])
        v2f a0 = b2p[0], a1 = b2p[1];
#pragma unroll
        for (int q = 0; q < H_/2; ++q) {
            asm("v_pk_fma_f32 %0, %1, %2, %0 op_sel:[0,0,0] op_sel_hi:[0,1,1]"
                : "+v"(a0) : "v"(h2[q]), "v"(w2p[2*q][0]));
            asm("v_pk_fma_f32 %0, %1, %2, %0 op_sel:[0,0,0] op_sel_hi:[0,1,1]"
                : "+v"(a1) : "v"(h2[q]), "v"(w2p[2*q][1]));
            asm("v_pk_fma_f32 %0, %1, %2, %0 op_sel:[1,0,0] op_sel_hi:[1,1,1]"
                : "+v"(a0) : "v"(h2[q]), "v"(w2p[2*q+1][0]));
            asm("v_pk_fma_f32 %0, %1, %2, %0 op_sel:[1,0,0] op_sel_hi:[1,1,1]"
                : "+v"(a1) : "v"(h2[q]), "v"(w2p[2*q+1][1]));
        }

        v4f acc = {a0.x, a0.y, a1.x, a1.y};
        out4[r * rowstride4 + tid] = acc;   // plain store, sliding window
    }
}

extern "C" void kernel_launch(void* const* d_in, const int* in_sizes, int n_in,
                              void* d_out, int out_size, void* d_ws, size_t ws_size,
                              hipStream_t stream) {
    const float* x  = (const float*)d_in[0];
    const float* W1 = (const float*)d_in[1];
    const float* b1 = (const float*)d_in[2];
    const float* W2 = (const float*)d_in[3];
    const float* b2 = (const float*)d_in[4];
    float* out = (float*)d_out;

    dim3 grid(NBLK);   // 512 blocks; rows grid-stride interleaved
    nfe_kernel<<<grid, NTHREADS, 0, stream>>>(x, W1, b1, W2, b2, out);
}

// Round 13
// 60.383 us; speedup vs baseline: 1.3982x; 1.3963x over previous
//
#include <hip/hip_runtime.h>

#define F_   128
#define H_   16
#define E_   32
#define FG   8     // features per wave
#define BPW  8     // b rows per wave -- ALL x preloaded to registers
#define WAVES 4
#define NTHREADS (WAVES * 64)   // 256

typedef float v2f __attribute__((ext_vector_type(2)));
typedef float v4f __attribute__((ext_vector_type(4)));

// Champion compute (packed fp32, nt stores, strided layout) with ONE change:
// NO LOADS in the steady state. Each wave preloads its 8 x values (+8 VGPR,
// total ~118 -> still 16 waves/CU), then 8 fully-unrolled iterations of pure
// {VALU + nt store}. No load -> no s_waitcnt in the store stream -> stores
// free-run up to 8-deep per wave (fill-kernel-like), instead of the
// champion's per-iter vmcnt wait chaining stores to x-load returns.
__global__ __launch_bounds__(NTHREADS, 4)
void nfe_kernel(const float* __restrict__ x,
                const float* __restrict__ W1,
                const float* __restrict__ b1,
                const float* __restrict__ W2,
                const float* __restrict__ b2,
                float* __restrict__ out)
{
    const int tid  = threadIdx.x;
    const int wave = tid >> 6;
    const int lane = tid & 63;

    const int f0 = blockIdx.x * FG;
    const int b0 = (blockIdx.y * WAVES + wave) * BPW;

    const int f  = f0 + (lane >> 3);
    const int e4 = lane & 7;

    // ---- preload ALL x for this wave's 8 b's (8 VGPR) ----
    const float* xp = x + (size_t)b0 * F_ + f;
    float xv[BPW];
#pragma unroll
    for (int k = 0; k < BPW; ++k) xv[k] = xp[k * F_];

    // ---- per-lane weight fragments in registers (as f32 pairs) ----
    v2f w1p[H_/2], b1p[H_/2];
    {
        const v2f* p1 = (const v2f*)(W1 + f * H_);
        const v2f* p2 = (const v2f*)(b1 + f * H_);
#pragma unroll
        for (int q = 0; q < H_/2; ++q) { w1p[q] = p1[q]; b1p[q] = p2[q]; }
    }
    v2f w2p[H_][2];   // [j][e-pair], covers this lane's 4 e's
#pragma unroll
    for (int j = 0; j < H_; ++j) {
        const v2f* q = (const v2f*)(W2 + (f * H_ + j) * E_ + e4 * 4);
        w2p[j][0] = q[0]; w2p[j][1] = q[1];
    }
    v2f b2p[2];
    {
        const v2f* q = (const v2f*)(b2 + f * E_ + e4 * 4);
        b2p[0] = q[0]; b2p[1] = q[1];
    }

    // ---- pure compute + store loop: ZERO loads, ZERO forced waits ----
    v4f* op = (v4f*)out + (size_t)b0 * (F_ * E_ / 4)
            + f0 * (E_ / 4) + lane;
    const int ostride = F_ * E_ / 4;   // v4f per b-row

    const v2f zero2 = {0.0f, 0.0f};

#pragma unroll
    for (int i = 0; i < BPW; ++i) {
        const float xs = xv[i];
        v2f x2 = {xs, xs};
        v2f h2[H_/2];
#pragma unroll
        for (int q = 0; q < H_/2; ++q) {
            v2f t = __builtin_elementwise_fma(x2, w1p[q], b1p[q]);
            h2[q] = __builtin_elementwise_max(t, zero2);
        }
        v2f a0 = b2p[0], a1 = b2p[1];
#pragma unroll
        for (int q = 0; q < H_/2; ++q) {
            asm("v_pk_fma_f32 %0, %1, %2, %0 op_sel:[0,0,0] op_sel_hi:[0,1,1]"
                : "+v"(a0) : "v"(h2[q]), "v"(w2p[2*q][0]));
            asm("v_pk_fma_f32 %0, %1, %2, %0 op_sel:[0,0,0] op_sel_hi:[0,1,1]"
                : "+v"(a1) : "v"(h2[q]), "v"(w2p[2*q][1]));
            asm("v_pk_fma_f32 %0, %1, %2, %0 op_sel:[1,0,0] op_sel_hi:[1,1,1]"
                : "+v"(a0) : "v"(h2[q]), "v"(w2p[2*q+1][0]));
            asm("v_pk_fma_f32 %0, %1, %2, %0 op_sel:[1,0,0] op_sel_hi:[1,1,1]"
                : "+v"(a1) : "v"(h2[q]), "v"(w2p[2*q+1][1]));
        }
        v4f acc = {a0.x, a0.y, a1.x, a1.y};
        __builtin_nontemporal_store(acc, op + i * ostride);
    }
}

extern "C" void kernel_launch(void* const* d_in, const int* in_sizes, int n_in,
                              void* d_out, int out_size, void* d_ws, size_t ws_size,
                              hipStream_t stream) {
    const float* x  = (const float*)d_in[0];
    const float* W1 = (const float*)d_in[1];
    const float* b1 = (const float*)d_in[2];
    const float* W2 = (const float*)d_in[3];
    const float* b2 = (const float*)d_in[4];
    float* out = (float*)d_out;

    const int B = in_sizes[0] / F_;                 // 16384
    dim3 grid(F_ / FG, B / (BPW * WAVES));          // (16, 512)
    nfe_kernel<<<grid, NTHREADS, 0, stream>>>(x, W1, b1, W2, b2, out);
}

// Round 14
// 56.621 us; speedup vs baseline: 1.4911x; 1.0664x over previous
//
#include <hip/hip_runtime.h>

#define F_   128
#define H_   16
#define E_   32
#define FG   8     // features per wave
#define BPW  64    // b rows per wave
#define WAVES 4
#define NTHREADS (WAVES * 64)   // 256

typedef float v2f __attribute__((ext_vector_type(2)));
typedef float v4f __attribute__((ext_vector_type(4)));

// FINAL (champion, R6, 55.0 us = 4.8 TB/s effective — within ~2% of the
// best real-kernel HBM BW measured on MI355X, cf. learn_hip m146 RMSNorm
// 4.89 TB/s). Wave owns 8 features x 64 b; lane -> (f, e-quad). Weights in
// registers; per b one coalesced 1 KB nt wave-store; packed-fp32 math
// (v_pk_fma_f32 with op_sel h-broadcast); distance-1 x prefetch.
// Falsified levers: plain stores (+11..+29 us), linear/sliding write
// patterns (+5..+29), deeper store pipelines (+3..+66), LDS staging (+7),
// zero-load steady state (+5), occupancy variants. This is the roofline.
__global__ __launch_bounds__(NTHREADS, 4)
void nfe_kernel(const float* __restrict__ x,
                const float* __restrict__ W1,
                const float* __restrict__ b1,
                const float* __restrict__ W2,
                const float* __restrict__ b2,
                float* __restrict__ out)
{
    const int tid  = threadIdx.x;
    const int wave = tid >> 6;
    const int lane = tid & 63;

    const int f0 = blockIdx.x * FG;
    const int b0 = (blockIdx.y * WAVES + wave) * BPW;

    const int f  = f0 + (lane >> 3);
    const int e4 = lane & 7;

    // ---- per-lane weight fragments in registers (as f32 pairs) ----
    v2f w1p[H_/2], b1p[H_/2];
    {
        const v2f* p1 = (const v2f*)(W1 + f * H_);
        const v2f* p2 = (const v2f*)(b1 + f * H_);
#pragma unroll
        for (int q = 0; q < H_/2; ++q) { w1p[q] = p1[q]; b1p[q] = p2[q]; }
    }
    v2f w2p[H_][2];   // [j][e-pair], covers this lane's 4 e's
#pragma unroll
    for (int j = 0; j < H_; ++j) {
        const v2f* q = (const v2f*)(W2 + (f * H_ + j) * E_ + e4 * 4);
        w2p[j][0] = q[0]; w2p[j][1] = q[1];
    }
    v2f b2p[2];
    {
        const v2f* q = (const v2f*)(b2 + f * E_ + e4 * 4);
        b2p[0] = q[0]; b2p[1] = q[1];
    }

    // ---- streaming loop over b ----
    const float* xp = x + (size_t)b0 * F_ + f;
    v4f* op = (v4f*)out + (size_t)b0 * (F_ * E_ / 4)
            + f0 * (E_ / 4) + lane;

    const v2f zero2 = {0.0f, 0.0f};

    float xv_next = *xp;
#pragma unroll 2
    for (int i = 0; i < BPW; ++i) {
        const float xv = xv_next;
        if (i + 1 < BPW) xv_next = xp[(i + 1) * F_];   // prefetch next b

        // layer 1: h pairs
        v2f x2 = {xv, xv};
        v2f h2[H_/2];
#pragma unroll
        for (int q = 0; q < H_/2; ++q) {
            v2f t = __builtin_elementwise_fma(x2, w1p[q], b1p[q]);
            h2[q] = __builtin_elementwise_max(t, zero2);
        }

        // layer 2: acc pairs, h broadcast via op_sel (lo then hi of h2[q])
        v2f a0 = b2p[0], a1 = b2p[1];
#pragma unroll
        for (int q = 0; q < H_/2; ++q) {
            asm("v_pk_fma_f32 %0, %1, %2, %0 op_sel:[0,0,0] op_sel_hi:[0,1,1]"
                : "+v"(a0) : "v"(h2[q]), "v"(w2p[2*q][0]));
            asm("v_pk_fma_f32 %0, %1, %2, %0 op_sel:[0,0,0] op_sel_hi:[0,1,1]"
                : "+v"(a1) : "v"(h2[q]), "v"(w2p[2*q][1]));
            asm("v_pk_fma_f32 %0, %1, %2, %0 op_sel:[1,0,0] op_sel_hi:[1,1,1]"
                : "+v"(a0) : "v"(h2[q]), "v"(w2p[2*q+1][0]));
            asm("v_pk_fma_f32 %0, %1, %2, %0 op_sel:[1,0,0] op_sel_hi:[1,1,1]"
                : "+v"(a1) : "v"(h2[q]), "v"(w2p[2*q+1][1]));
        }

        v4f acc = {a0.x, a0.y, a1.x, a1.y};
        __builtin_nontemporal_store(acc, op + i * (F_ * E_ / 4));
    }
}

extern "C" void kernel_launch(void* const* d_in, const int* in_sizes, int n_in,
                              void* d_out, int out_size, void* d_ws, size_t ws_size,
                              hipStream_t stream) {
    const float* x  = (const float*)d_in[0];
    const float* W1 = (const float*)d_in[1];
    const float* b1 = (const float*)d_in[2];
    const float* W2 = (const float*)d_in[3];
    const float* b2 = (const float*)d_in[4];
    float* out = (float*)d_out;

    const int B = in_sizes[0] / F_;                 // 16384
    dim3 grid(F_ / FG, B / (BPW * WAVES));          // (16, 64)
    nfe_kernel<<<grid, NTHREADS, 0, stream>>>(x, W1, b1, W2, b2, out);
}